// Round 9
// baseline (289.664 us; speedup 1.0000x reference)
//
#include <hip/hip_runtime.h>
#include <hip/hip_bf16.h>
#include <math.h>

#define B_ 2
#define S_ 2048
#define D_ 2048
#define NH_ 16
#define NKV_ 4
#define HD_ 128
#define EPS_ 1e-6f
#define SCALE_ 0.08838834764831845f  // 1/sqrt(128)
#define LOG2E_ 1.4426950408889634f
#define KOFF_ 2048                   // k rows offset in fused Wt
#define VOFF_ 2560                   // v rows offset in fused Wt
#define MINIT_ -1e30f                // finite "-inf" so exp2 paths never NaN

typedef float f32x4 __attribute__((ext_vector_type(4)));
typedef short bf16x8 __attribute__((ext_vector_type(8)));
typedef short short4v __attribute__((ext_vector_type(4)));
typedef float float4v __attribute__((ext_vector_type(4)));
typedef unsigned uint2v __attribute__((ext_vector_type(2)));
typedef unsigned uint4v __attribute__((ext_vector_type(4)));

static __device__ __forceinline__ short f2bf(float f) {
    union { float f; unsigned u; } x{f};
    unsigned r = (x.u + 0x7fff + ((x.u >> 16) & 1)) >> 16;   // RTNE
    return (short)r;
}
static __device__ __forceinline__ float bf2f(short s) {
    union { unsigned u; float f; } x; x.u = ((unsigned)(unsigned short)s) << 16; return x.f;
}
// pack two fp32 -> two bf16 (truncation) in ONE v_perm: lo16=hi16(a), hi16=hi16(b)
static __device__ __forceinline__ unsigned pack_bf2(float a, float b) {
    return __builtin_amdgcn_perm(__builtin_bit_cast(unsigned, b),
                                 __builtin_bit_cast(unsigned, a), 0x07060302u);
}

#define AS1(p) ((const __attribute__((address_space(1))) void*)(p))
#define AS3(p) ((__attribute__((address_space(3))) void*)(p))
static __device__ __forceinline__ void async16(const void* g, void* l) {
    __builtin_amdgcn_global_load_lds(AS1(g), AS3(l), 16, 0, 0);
}
#define SB_() __builtin_amdgcn_sched_barrier(0)

// ---------------------------------------------------------------------------
// fp32 -> bf16 flat cast (for x). 4 elems/thread.
// ---------------------------------------------------------------------------
__global__ __launch_bounds__(256) void cast_kernel(const float* __restrict__ in,
                                                   short* __restrict__ out) {
    size_t i = ((size_t)blockIdx.x * 256 + threadIdx.x) * 4;
    float4v v = *(const float4v*)(in + i);
    short4v o; o.x = f2bf(v.x); o.y = f2bf(v.y); o.z = f2bf(v.z); o.w = f2bf(v.w);
    *(short4v*)(out + i) = o;
}

// ---------------------------------------------------------------------------
// All 4 weight transposes in ONE launch. fp32 [K=2048][N] -> bf16 [N][2048].
// grid (80, 32): bx<32 Wq | <40 Wk | <48 Wv | else Wo.
// ---------------------------------------------------------------------------
__global__ __launch_bounds__(256) void transpose_all_kernel(const float* __restrict__ Wq,
                                                            const float* __restrict__ Wk,
                                                            const float* __restrict__ Wv,
                                                            const float* __restrict__ Wo,
                                                            short* __restrict__ Wt,
                                                            short* __restrict__ Wot) {
    __shared__ float tile[64][65];
    const int bx = blockIdx.x, by = blockIdx.y;
    const float* src; short* dst; int N, nb;
    if (bx < 32)      { src = Wq; dst = Wt;                         N = 2048; nb = bx; }
    else if (bx < 40) { src = Wk; dst = Wt + (size_t)KOFF_ * 2048;  N = 512;  nb = bx - 32; }
    else if (bx < 48) { src = Wv; dst = Wt + (size_t)VOFF_ * 2048;  N = 512;  nb = bx - 40; }
    else              { src = Wo; dst = Wot;                        N = 2048; nb = bx - 48; }
    const int n0 = nb * 64, k0 = by * 64;
    const int tid = threadIdx.x;
    for (int r = 0; r < 16; ++r) {
        int k = r * 4 + (tid >> 6);
        int n = tid & 63;
        tile[k][n] = src[(size_t)(k0 + k) * N + n0 + n];
    }
    __syncthreads();
    for (int r = 0; r < 4; ++r) {
        int n  = r * 16 + (tid >> 4);
        int kk = (tid & 15) * 4;
        short4v o4;
        o4.x = f2bf(tile[kk + 0][n]); o4.y = f2bf(tile[kk + 1][n]);
        o4.z = f2bf(tile[kk + 2][n]); o4.w = f2bf(tile[kk + 3][n]);
        *(short4v*)&dst[(size_t)(n0 + n) * 2048 + k0 + kk] = o4;
    }
}

// ---------------------------------------------------------------------------
// O-proj GEMM: C[4096][2048] fp32 = a_out[4096][2048]bf16 @ Wot[2048][2048]^T.
// Tile 128x256, BK=64, 2 K-tiles/iter, 16 iters. grid (8,32) = 256 blocks.
// (unchanged from round 8)
// ---------------------------------------------------------------------------
__global__ __launch_bounds__(512, 2) void gemm_oproj_kernel(const short* __restrict__ A,
                                                            const short* __restrict__ Bt,
                                                            float* __restrict__ C) {
    __shared__ __align__(16) short smem[49152];   // 96KB
    short* A0 = smem;            // 128x64
    short* A1 = smem + 8192;
    short* B0 = smem + 16384;    // 256x64
    short* B1 = smem + 32768;

    const int tid  = threadIdx.x;
    const int orig = blockIdx.y * 8 + blockIdx.x;       // 0..255
    const int swz  = (orig & 7) * 32 + (orig >> 3);     // XCD chunking (256%8==0)
    const int bn = swz & 7, bm = swz >> 3;
    const int wave = tid >> 6, lane = tid & 63;
    const int quad = lane >> 4, l16 = lane & 15;
    const int wr = wave >> 2, wc = wave & 3;            // 2M x 4N waves

    const short* Ag = A  + (size_t)(bm * 128) * 2048;
    const short* Bg = Bt + (size_t)(bn * 256) * 2048;

    f32x4 acc[4][4];
#pragma unroll
    for (int i = 0; i < 4; ++i)
#pragma unroll
        for (int j = 0; j < 4; ++j) acc[i][j] = (f32x4){0.f, 0.f, 0.f, 0.f};

    bf16x8 a[4][2], b0[2][2], b1[2][2];

    auto stage_half = [&](const short* gpanel, int t, int h, short* lslot) {
#pragma unroll
        for (int u = 0; u < 2; ++u) {
            int ci = u * 512 + tid;
            int r  = ci >> 3;
            int cb = ((ci & 7) * 16) ^ ((r & 7) << 4);
            async16(gpanel + (size_t)(h * 128 + r) * 2048 + t * 64 + (cb >> 1),
                    lslot + h * 8192 + ci * 8);
        }
    };

#define OLDA_(lbuf) \
    _Pragma("unroll") for (int mt = 0; mt < 4; ++mt) \
    _Pragma("unroll") for (int ks = 0; ks < 2; ++ks) { \
        int row_ = wr * 64 + mt * 16 + l16; \
        int cb_  = (ks * 64 + quad * 16) ^ ((row_ & 7) << 4); \
        a[mt][ks] = *(const bf16x8*)&(lbuf)[row_ * 64 + (cb_ >> 1)]; \
    }
#define OLDB_(lbuf, qn, breg) \
    _Pragma("unroll") for (int ntl = 0; ntl < 2; ++ntl) \
    _Pragma("unroll") for (int ks = 0; ks < 2; ++ks) { \
        int row_ = wc * 64 + (qn) * 32 + ntl * 16 + l16; \
        int cb_  = (ks * 64 + quad * 16) ^ ((row_ & 7) << 4); \
        breg[ntl][ks] = *(const bf16x8*)&(lbuf)[row_ * 64 + (cb_ >> 1)]; \
    }
#define OBAR_() __builtin_amdgcn_s_barrier()
#define OMFMA_(qn, breg) do { \
    __builtin_amdgcn_s_setprio(1); \
    _Pragma("unroll") for (int mt = 0; mt < 4; ++mt) \
    _Pragma("unroll") for (int ntl = 0; ntl < 2; ++ntl) \
    _Pragma("unroll") for (int ks = 0; ks < 2; ++ks) \
        acc[mt][(qn) * 2 + ntl] = __builtin_amdgcn_mfma_f32_16x16x32_bf16( \
            a[mt][ks], breg[ntl][ks], acc[mt][(qn) * 2 + ntl], 0, 0, 0); \
    __builtin_amdgcn_s_setprio(0); __builtin_amdgcn_s_barrier(); } while (0)

    // prologue: B0(t0) + A0(t0) = 6 ops; full drain
    stage_half(Bg, 0, 0, B0); stage_half(Bg, 0, 1, B0);
    stage_half(Ag, 0, 0, A0);
    asm volatile("s_waitcnt vmcnt(0)" ::: "memory");
    __builtin_amdgcn_s_barrier();

#pragma unroll 1
    for (int i = 0; i < 16; ++i) {
        const int tE = 2 * i, tO = 2 * i + 1;
        const bool more = (i < 15);

        // P1: stage A1(tO)+B1(tO); read aE, bE-h0; bar; MFMA
        stage_half(Ag, tO, 0, A1);
        stage_half(Bg, tO, 0, B1); stage_half(Bg, tO, 1, B1);
        OLDA_(A0); OLDB_(B0, 0, b0);
        OBAR_();
        OMFMA_(0, b0);

        // P2: stage A0(tE+2); vmcnt(2) drains A1,B1; read bE-h1; bar; MFMA
        if (more) {
            stage_half(Ag, tE + 2, 0, A0);
            asm volatile("s_waitcnt vmcnt(2)" ::: "memory");
        } else {
            asm volatile("s_waitcnt vmcnt(0)" ::: "memory");
        }
        OLDB_(B0, 1, b1);
        OBAR_();
        OMFMA_(1, b1);

        // P3: stage B0(tE+2); read aO, bO-h0; bar; MFMA
        if (more) { stage_half(Bg, tE + 2, 0, B0); stage_half(Bg, tE + 2, 1, B0); }
        OLDA_(A1); OLDB_(B1, 0, b0);
        OBAR_();
        OMFMA_(0, b0);

        // P4: vmcnt(0) drains A0',B0' for next P1; read bO-h1; bar; MFMA
        if (more) { asm volatile("s_waitcnt vmcnt(0)" ::: "memory"); }
        OLDB_(B1, 1, b1);
        OBAR_();
        OMFMA_(1, b1);
    }

    // epilogue: direct fp32 store
#pragma unroll
    for (int mt = 0; mt < 4; ++mt)
#pragma unroll
        for (int nt = 0; nt < 4; ++nt)
#pragma unroll
            for (int j = 0; j < 4; ++j) {
                int row = bm * 128 + wr * 64 + mt * 16 + quad * 4 + j;
                int col = bn * 256 + wc * 64 + nt * 16 + l16;
                C[(size_t)row * 2048 + col] = acc[mt][nt][j];
            }
#undef OLDA_
#undef OLDB_
#undef OBAR_
#undef OMFMA_
}

// ---------------------------------------------------------------------------
// Fused QKV GEMM + RMSNorm + RoPE + V-transpose — r9: tile 128x384, grid
// (8 bn, 32 bm) = 256 uniform blocks = FULL machine (was 192/256 CUs).
// 384 cols = 3 heads (head-aligned). 8 waves as 2M x 4N; wave-tile 64x96
// (4mt x 6nt). LDS 128KB: A[2][128x64] 32KB + B[2][384x64] 96KB.
// Stage units of 128 rows (A=1u, B=3u per K-tile); r3-style 2-barrier
// phases with counted vmcnt:
//   P1: read A0,B0n0 | stage B1(tO) x3          | bar | MFMA24
//   P2: read B0n1    | stage A0'(tE+2); vmcnt(2)| bar | MFMA24
//   P3: read A1,B1n0 | stage B0'(tE+2) x3       | bar | MFMA24
//   P4: read B1n1    | stage A1'(tO+2); vmcnt(2)| bar | MFMA24
// Epilogue: V heads stored directly from acc (transposed 8B runs); Q/K via
// LDS C-tile [128][386], one thread per (row,head): sumsq+RMS+RoPE.
// ---------------------------------------------------------------------------
#define QKV_ITERS 16   // K=2048 / (2 K-tiles * 64)

__global__ __launch_bounds__(512, 2) void qkv_fused_kernel(const short* __restrict__ xb,
                                                           const short* __restrict__ Wt,
                                                           const float* __restrict__ cosb,
                                                           const float* __restrict__ sinb,
                                                           const float* __restrict__ qw,
                                                           const float* __restrict__ kw,
                                                           short* __restrict__ q_rope,
                                                           short* __restrict__ k_rope,
                                                           short* __restrict__ vtr) {
    __shared__ __align__(16) short smem[65536];   // 128KB: A0|A1|B0|B1, then C tile

    short* A0 = smem;             // [128][64]
    short* A1 = smem + 8192;
    short* B0 = smem + 16384;     // [384][64]
    short* B1 = smem + 40960;

    const int tid  = threadIdx.x;
    const int orig = blockIdx.y * 8 + blockIdx.x;       // 0..255
    const int swz  = (orig & 7) * 32 + (orig >> 3);     // XCD x -> bn=x chunk
    const int bn = swz >> 5, bm = swz & 31;             // bn 0..7, bm 0..31
    const int wave = tid >> 6, lane = tid & 63;
    const int quad = lane >> 4, l16 = lane & 15;
    const int wr = wave >> 2, wc = wave & 3;            // 2M x 4N waves

    const short* Ag = xb + (size_t)(bm * 128) * 2048;
    const short* Bg = Wt + (size_t)(bn * 384) * 2048;

    f32x4 acc[4][6];
#pragma unroll
    for (int i = 0; i < 4; ++i)
#pragma unroll
        for (int j = 0; j < 6; ++j) acc[i][j] = (f32x4){0.f, 0.f, 0.f, 0.f};

    bf16x8 a[4][2], b0[3][2], b1[3][2];

    // stage one 128-row x 64-col unit; LDS dest linear, global source
    // inverse-swizzled so swizzled ds_reads return true data.
    auto stage_half = [&](const short* gpanel, int t, int h, short* lslot) {
#pragma unroll
        for (int u = 0; u < 2; ++u) {
            int ci = u * 512 + tid;                 // 0..1023
            int r  = ci >> 3;                       // 0..127
            int cb = ((ci & 7) * 16) ^ ((r & 7) << 4);
            async16(gpanel + (size_t)(h * 128 + r) * 2048 + t * 64 + (cb >> 1),
                    lslot + h * 8192 + ci * 8);
        }
    };

#define LDA_(lbuf) \
    _Pragma("unroll") for (int mt = 0; mt < 4; ++mt) \
    _Pragma("unroll") for (int ks = 0; ks < 2; ++ks) { \
        int row_ = wr * 64 + mt * 16 + l16; \
        int cb_  = (ks * 64 + quad * 16) ^ ((row_ & 7) << 4); \
        a[mt][ks] = *(const bf16x8*)&(lbuf)[row_ * 64 + (cb_ >> 1)]; \
    }
#define LDB_(lbuf, qn, breg) \
    _Pragma("unroll") for (int ntl = 0; ntl < 3; ++ntl) \
    _Pragma("unroll") for (int ks = 0; ks < 2; ++ks) { \
        int row_ = wc * 96 + (qn) * 48 + ntl * 16 + l16; \
        int cb_  = (ks * 64 + quad * 16) ^ ((row_ & 7) << 4); \
        breg[ntl][ks] = *(const bf16x8*)&(lbuf)[row_ * 64 + (cb_ >> 1)]; \
    }
#define PH_BAR() do { __builtin_amdgcn_sched_barrier(0); __builtin_amdgcn_s_barrier(); } while (0)
#define PH_MFMA24(qn, breg) do { \
        __builtin_amdgcn_s_setprio(1); \
        _Pragma("unroll") for (int mt = 0; mt < 4; ++mt) \
        _Pragma("unroll") for (int ntl = 0; ntl < 3; ++ntl) \
        _Pragma("unroll") for (int ks = 0; ks < 2; ++ks) \
            acc[mt][(qn) * 3 + ntl] = __builtin_amdgcn_mfma_f32_16x16x32_bf16( \
                a[mt][ks], breg[ntl][ks], acc[mt][(qn) * 3 + ntl], 0, 0, 0); \
        __builtin_amdgcn_s_setprio(0); \
        __builtin_amdgcn_sched_barrier(0); __builtin_amdgcn_s_barrier(); } while (0)

    // prologue: B0(t0) 3u + A0(t0) 1u + A1(t1) 1u = 10 loads/thread;
    // vmcnt(2) drains B0,A0; A1 stays in flight (drained at P2).
    stage_half(Bg, 0, 0, B0); stage_half(Bg, 0, 1, B0); stage_half(Bg, 0, 2, B0);
    stage_half(Ag, 0, 0, A0);
    stage_half(Ag, 1, 0, A1);
    asm volatile("s_waitcnt vmcnt(2)" ::: "memory");
    __builtin_amdgcn_s_barrier();

#pragma unroll 1
    for (int i = 0; i < QKV_ITERS; ++i) {
        const int tE = 2 * i, tO = 2 * i + 1;
        const bool more = (i < QKV_ITERS - 1);

        // P1: read A0 (all) + B0 n-half 0; stage B1(tO) x3
        LDA_(A0); LDB_(B0, 0, b0);
        stage_half(Bg, tO, 0, B1); stage_half(Bg, tO, 1, B1); stage_half(Bg, tO, 2, B1);
        PH_BAR();
        PH_MFMA24(0, b0);

        // P2: read B0 n-half 1; stage A0'(tE+2); vmcnt drains A1+B1(tO)
        LDB_(B0, 1, b1);
        if (more) {
            stage_half(Ag, tE + 2, 0, A0);
            asm volatile("s_waitcnt vmcnt(2)" ::: "memory");
        } else {
            asm volatile("s_waitcnt vmcnt(0)" ::: "memory");
        }
        PH_BAR();
        PH_MFMA24(1, b1);

        // P3: read A1 (all) + B1 n-half 0; stage B0'(tE+2) x3
        LDA_(A1); LDB_(B1, 0, b0);
        if (more) { stage_half(Bg, tE + 2, 0, B0); stage_half(Bg, tE + 2, 1, B0); stage_half(Bg, tE + 2, 2, B0); }
        PH_BAR();
        PH_MFMA24(0, b0);

        // P4: read B1 n-half 1; stage A1'(tO+2); vmcnt drains A0'+B0'
        LDB_(B1, 1, b1);
        if (more) {
            stage_half(Ag, tO + 2, 0, A1);
            asm volatile("s_waitcnt vmcnt(2)" ::: "memory");
        }
        PH_BAR();
        PH_MFMA24(1, b1);
    }

    // ----------------------- epilogue -----------------------
    // V heads (gh 20..23): direct transposed store from acc, 8B 4-token runs.
#pragma unroll
    for (int mt = 0; mt < 4; ++mt) {
        int tok0 = bm * 128 + wr * 64 + mt * 16 + quad * 4;
        int bb = tok0 >> 11, s0 = tok0 & (S_ - 1);
#pragma unroll
        for (int nt = 0; nt < 6; ++nt) {
            int colh = wc * 96 + nt * 16;          // 16-aligned -> head-uniform
            int gh = bn * 3 + (colh >> 7);
            if (gh >= 20) {
                int g = gh - 20;
                int d = (colh & 127) + l16;
                short4v o4;
                o4.x = f2bf(acc[mt][nt][0]); o4.y = f2bf(acc[mt][nt][1]);
                o4.z = f2bf(acc[mt][nt][2]); o4.w = f2bf(acc[mt][nt][3]);
                *(short4v*)&vtr[((size_t)(bb * NKV_ + g) * HD_ + d) * S_ + s0] = o4;
            }
        }
    }
    if (bn * 3 >= 20) return;   // bn=7: pure-V block, done

    // Q/K: dump bf16 C tile to LDS [128][386] (stride 386 -> 2-way-free banks)
    short* ct = smem;
#pragma unroll
    for (int mt = 0; mt < 4; ++mt)
#pragma unroll
        for (int nt = 0; nt < 6; ++nt)
#pragma unroll
            for (int j = 0; j < 4; ++j)
                ct[(wr * 64 + mt * 16 + quad * 4 + j) * 386 + wc * 96 + nt * 16 + l16]
                    = f2bf(acc[mt][nt][j]);
    __syncthreads();

    // one thread per (head, row): sumsq -> RMS -> RoPE -> store
    if (tid < 384) {
        int hh = tid >> 7, row = tid & 127;
        int gh = bn * 3 + hh;
        if (gh < 20) {
            const bool isQ = gh < 16;
            const float osc = isQ ? (SCALE_ * LOG2E_) : 1.0f;
            const float* w = isQ ? qw : kw;
            const short* src = &ct[row * 386 + hh * 128];
            bf16x8 rv[16];
#pragma unroll
            for (int i = 0; i < 16; ++i) rv[i] = *(const bf16x8*)(src + i * 8);
            float ss = 0.f;
#pragma unroll
            for (int i = 0; i < 16; ++i)
#pragma unroll
                for (int j = 0; j < 8; ++j) { float f = bf2f(rv[i][j]); ss += f * f; }
            float rstd = rsqrtf(ss * (1.0f / HD_) + EPS_);
            int tok = bm * 128 + row;
            int bb = tok >> 11, s = tok & (S_ - 1);
            short* dst = isQ
                ? q_rope + ((size_t)(bb * S_ + s) * NH_ + gh) * HD_
                : k_rope + ((size_t)(bb * NKV_ + (gh - 16)) * S_ + s) * HD_;
#pragma unroll
            for (int sg = 0; sg < 16; ++sg) {
                int c0 = sg * 8, p0 = (sg ^ 8) * 8;
                bf16x8 ta = rv[sg], tb = rv[sg ^ 8];
                float sgn = (sg < 8) ? -1.0f : 1.0f;
                float4v cs0 = *(const float4v*)&cosb[(size_t)s * HD_ + c0];
                float4v cs1 = *(const float4v*)&cosb[(size_t)s * HD_ + c0 + 4];
                float4v sn0 = *(const float4v*)&sinb[(size_t)s * HD_ + c0];
                float4v sn1 = *(const float4v*)&sinb[(size_t)s * HD_ + c0 + 4];
                float ov[8];
#pragma unroll
                for (int i = 0; i < 8; ++i) {
                    float n1 = bf2f(ta[i]) * rstd * w[c0 + i];
                    float n2 = bf2f(tb[i]) * rstd * w[p0 + i];
                    float cs = (i < 4) ? cs0[i & 3] : cs1[i & 3];
                    float sn = (i < 4) ? sn0[i & 3] : sn1[i & 3];
                    ov[i] = (n1 * cs + sgn * n2 * sn) * osc;
                }
                uint4v wv;
#pragma unroll
                for (int i2 = 0; i2 < 4; ++i2)
                    wv[i2] = ((unsigned)(unsigned short)f2bf(ov[2 * i2])) |
                             ((unsigned)(unsigned short)f2bf(ov[2 * i2 + 1]) << 16);
                *(uint4v*)(dst + c0) = wv;
            }
        }
    }
#undef LDA_
#undef LDB_
#undef PH_BAR
#undef PH_MFMA24
}

// ---------------------------------------------------------------------------
// Flash causal GQA attention v7: dual-stream K parity split (unchanged r7).
// ---------------------------------------------------------------------------
__global__ __launch_bounds__(512, 1) void attn_kernel(const short* __restrict__ qr,
                                                      const short* __restrict__ kg,
                                                      const short* __restrict__ vt,
                                                      short* __restrict__ aout) {
    __shared__ __align__(16) short Ks[2][2][8192];   // [stream][dbuf][64 keys x 128 d]
    __shared__ __align__(16) short Vs[2][2][8192];   // [stream][dbuf][128 d x 64 keys]

    const int lin = blockIdx.x;        // 0..255 ; lin&7 = (b,g) = XCD id -> KV L2-local
    const int b  = lin & 1;
    const int g  = (lin >> 1) & 3;
    const int hq = (lin >> 3) & 3;
    const int pr = lin >> 5;           // 0..7
    const int h  = g * 4 + hq;

    const int wave = threadIdx.x >> 6, lane = threadIdx.x & 63;
    const int quad = lane >> 4, l16 = lane & 15;
    const int half = wave >> 2;        // 0 = stream A (even kt), 1 = B (odd kt)
    const int ww   = wave & 3;

    const short* kbase = kg + (size_t)(b * NKV_ + g) * S_ * HD_;
    const short* vbase = vt + (size_t)(b * NKV_ + g) * HD_ * S_;

    // stage one 64-key K/V unit; all 8 waves participate (2+2 async16 each)
    auto stage = [&](int kt, short* Kd, short* Vd) {
        const short* kt_base = kbase + (size_t)kt * 64 * HD_;
        const short* vt_base = vbase + kt * 64;
#pragma unroll
        for (int t = 0; t < 2; ++t) {
            int ci  = (wave * 2 + t) * 64 + lane;
            int key = ci >> 4;
            int c   = (ci & 15) ^ ((key ^ (key >> 2)) & 15);
            async16(kt_base + key * HD_ + c * 8, Kd + ci * 8);
        }
#pragma unroll
        for (int t = 0; t < 2; ++t) {
            int ci = (wave * 2 + t) * 64 + lane;
            int d  = ci >> 3;
            int c  = (ci & 7) ^ (d & 7);
            async16(vt_base + (size_t)d * S_ + c * 8, Vd + ci * 8);
        }
    };

#pragma unroll 1
    for (int ph = 0; ph < 2; ++ph) {
        const int qt    = ph ? (15 - pr) : pr;     // 128-row Q tile
        const int nhalf = qt + 1;                  // units per stream
        const int qrow0 = qt * 128 + ww * 16 + l16;
        const int qrow1 = qrow0 + 64;

        bf16x8 qf[2][4];
#pragma unroll
        for (int qs = 0; qs < 2; ++qs) {
            const short* qp = qr + ((size_t)(b * S_ + (qs ? qrow1 : qrow0)) * NH_ + h) * HD_;
#pragma unroll
            for (int ks = 0; ks < 4; ++ks)
                qf[qs][ks] = *(const bf16x8*)(qp + ks * 32 + quad * 8);
        }

        f32x4 o[2][8];
#pragma unroll
        for (int qs = 0; qs < 2; ++qs)
#pragma unroll
            for (int i = 0; i < 8; ++i) o[qs][i] = (f32x4){0.f, 0.f, 0.f, 0.f};
        float m_i[2] = {MINIT_, MINIT_};
        float l_i[2] = {0.f, 0.f};

        // prologue: first unit of each stream
        stage(0, Ks[0][0], Vs[0][0]);
        stage(1, Ks[1][0], Vs[1][0]);
        int buf = 0;
#pragma unroll 1
        for (int i = 0; i < nhalf; ++i) {
            __syncthreads();   // drains vmcnt: staged units landed; prev reads done
            if (i + 1 < nhalf) {
                stage(2 * i + 2, Ks[0][buf ^ 1], Vs[0][buf ^ 1]);
                stage(2 * i + 3, Ks[1][buf ^ 1], Vs[1][buf ^ 1]);
            }
            const short* Kb = Ks[half][buf];
            const short* Vb = Vs[half][buf];
            const int ktm = 2 * i + half;

            f32x4 acc[2][4];
#pragma unroll
            for (int qs = 0; qs < 2; ++qs)
#pragma unroll
                for (int t = 0; t < 4; ++t) acc[qs][t] = (f32x4){0.f, 0.f, 0.f, 0.f};
            __builtin_amdgcn_s_setprio(1);
#pragma unroll
            for (int t = 0; t < 4; ++t) {
                int lk = ((t >> 1) << 5) + ((l16 >> 2) << 3) + ((t & 1) << 2) + (l16 & 3);
                const short* kp = &Kb[lk * 128];
                int pm = (lk ^ (lk >> 2)) & 15;
#pragma unroll
                for (int ks = 0; ks < 4; ++ks) {
                    bf16x8 kf = *(const bf16x8*)(kp + (((ks * 4 + quad) ^ pm) * 8));
                    acc[0][t] = __builtin_amdgcn_mfma_f32_16x16x32_bf16(kf, qf[0][ks], acc[0][t], 0, 0, 0);
                    acc[1][t] = __builtin_amdgcn_mfma_f32_16x16x32_bf16(kf, qf[1][ks], acc[1][t], 0, 0, 0);
                }
            }
            __builtin_amdgcn_s_setprio(0);
            const int key_base = ktm * 64;
#pragma unroll
            for (int qs = 0; qs < 2; ++qs) {
                int qmin = qt * 128 + qs * 64 + ww * 16;
                int qrow = qs ? qrow1 : qrow0;
                if (key_base + 63 > qmin) {
#pragma unroll
                    for (int t = 0; t < 4; ++t)
#pragma unroll
                        for (int j = 0; j < 4; ++j) {
                            int kl = key_base + ((t >> 1) << 5) + (quad << 3) + ((t & 1) << 2) + j;
                            if (kl > qrow) acc[qs][t][j] = -INFINITY;
                        }
                }
            }
            unsigned pk[2][2][4];
#pragma unroll
            for (int qs = 0; qs < 2; ++qs) {
                float mx = m_i[qs];
#pragma unroll
                for (int t = 0; t < 4; ++t)
#pragma unroll
                    for (int j = 0; j < 4; ++j) mx = fmaxf(mx, acc[qs][t][j]);
                mx = fmaxf(mx, __shfl_xor(mx, 16));
                mx = fmaxf(mx, __shfl_xor(mx, 32));
                float al = __builtin_amdgcn_exp2f(m_i[qs] - mx);
                m_i[qs] = mx;
                float rs = 0.f;
                float p[4][4];
#pragma unroll
                for (int t = 0; t < 4; ++t)
#pragma unroll
                    for (int j = 0; j < 4; ++j) {
                        float e = __builtin_amdgcn_exp2f(acc[qs][t][j] - mx);
                        p[t][j] = e;
                        rs += e;
                    }
                rs += __shfl_xor(rs, 16);
                rs += __shfl_xor(rs, 32);
                l_i[qs] = al * l_i[qs] + rs;
#pragma unroll
                for (int d8 = 0; d8 < 8; ++d8)
#pragma unroll
                    for (int j = 0; j < 4; ++j) o[qs][d8][j] *= al;
#pragma unroll
                for (int grp = 0; grp < 2; ++grp) {
                    pk[qs][grp][0] = pack_bf2(p[2 * grp][0],     p[2 * grp][1]);
                    pk[qs][grp][1] = pack_bf2(p[2 * grp][2],     p[2 * grp][3]);
                    pk[qs][grp][2] = pack_bf2(p[2 * grp + 1][0], p[2 * grp + 1][1]);
                    pk[qs][grp][3] = pack_bf2(p[2 * grp + 1][2], p[2 * grp + 1][3]);
                }
            }
            __builtin_amdgcn_s_setprio(1);
#pragma unroll
            for (int grp = 0; grp < 2; ++grp) {
                union { unsigned u[4]; bf16x8 v; } pb0, pb1;
#pragma unroll
                for (int i2 = 0; i2 < 4; ++i2) { pb0.u[i2] = pk[0][grp][i2]; pb1.u[i2] = pk[1][grp][i2]; }
#pragma unroll
                for (int d8 = 0; d8 < 8; ++d8) {
                    int d = d8 * 16 + l16;
                    bf16x8 vf = *(const bf16x8*)&Vb[d * 64 + (((grp * 4 + quad) ^ (d & 7)) * 8)];
                    o[0][d8] = __builtin_amdgcn_mfma_f32_16x16x32_bf16(vf, pb0.v, o[0][d8], 0, 0, 0);
                    o[1][d8] = __builtin_amdgcn_mfma_f32_16x16x32_bf16(vf, pb1.v, o[1][d8], 0, 0, 0);
                }
            }
            __builtin_amdgcn_s_setprio(0);
            buf ^= 1;
        }

        // ---- merge A/B partials via LDS exchange (staging buffers dead) ----
        __syncthreads();
        float* exch = (float*)(ww < 2 ? &Ks[0][0][0] : &Vs[0][0][0]);
        float* slot = exch + ((size_t)((ww & 1) * 64 + lane) * 68);
        if (half == 1) {
#pragma unroll
            for (int qs = 0; qs < 2; ++qs) {
#pragma unroll
                for (int d8 = 0; d8 < 8; ++d8)
#pragma unroll
                    for (int j = 0; j < 4; ++j)
                        slot[qs * 32 + d8 * 4 + j] = o[qs][d8][j];
                slot[64 + qs] = m_i[qs];
                slot[66 + qs] = l_i[qs];
            }
        }
        __syncthreads();
        if (half == 0) {
#pragma unroll
            for (int qs = 0; qs < 2; ++qs) {
                float mB = slot[64 + qs], lB = slot[66 + qs];
                float m  = fmaxf(m_i[qs], mB);
                float wA = __builtin_amdgcn_exp2f(m_i[qs] - m);
                float wB = __builtin_amdgcn_exp2f(mB - m);
                float il = 1.0f / (l_i[qs] * wA + lB * wB);
                int qrow = qs ? qrow1 : qrow0;
                short* op = aout + ((size_t)(b * S_ + qrow) * NH_ + h) * HD_ + quad * 4;
#pragma unroll
                for (int d8 = 0; d8 < 8; ++d8) {
                    float v0 = (o[qs][d8][0] * wA + slot[qs * 32 + d8 * 4 + 0] * wB) * il;
                    float v1 = (o[qs][d8][1] * wA + slot[qs * 32 + d8 * 4 + 1] * wB) * il;
                    float v2 = (o[qs][d8][2] * wA + slot[qs * 32 + d8 * 4 + 2] * wB) * il;
                    float v3 = (o[qs][d8][3] * wA + slot[qs * 32 + d8 * 4 + 3] * wB) * il;
                    uint2v wv;
                    wv.x = ((unsigned)(unsigned short)f2bf(v0)) |
                           ((unsigned)(unsigned short)f2bf(v1) << 16);
                    wv.y = ((unsigned)(unsigned short)f2bf(v2)) |
                           ((unsigned)(unsigned short)f2bf(v3) << 16);
                    *(uint2v*)(op + d8 * 16) = wv;
                }
            }
        }
        __syncthreads();   // exchange fully read before next phase restages
    }
}

// ---------------------------------------------------------------------------
extern "C" void kernel_launch(void* const* d_in, const int* in_sizes, int n_in,
                              void* d_out, int out_size, void* d_ws, size_t ws_size,
                              hipStream_t stream) {
    (void)in_sizes; (void)n_in; (void)out_size; (void)ws_size;
    const float* x    = (const float*)d_in[0];
    const float* cosb = (const float*)d_in[1];
    const float* sinb = (const float*)d_in[2];
    const float* Wq   = (const float*)d_in[3];
    const float* Wk   = (const float*)d_in[4];
    const float* Wv   = (const float*)d_in[5];
    const float* Wo   = (const float*)d_in[6];
    const float* qw   = (const float*)d_in[7];
    const float* kw   = (const float*)d_in[8];
    float* out = (float*)d_out;

    char* ws = (char*)d_ws;
    short* xb     = (short*)ws;  ws += (size_t)4096 * 2048 * 2;    // 16MB
    short* Wt     = (short*)ws;  ws += (size_t)3072 * 2048 * 2;    // 12MB [n][k]
    short* Wot    = (short*)ws;  ws += (size_t)2048 * 2048 * 2;    // 8MB  [n][k]
    short* q_rope = (short*)ws;  ws += (size_t)4096 * 2048 * 2;    // 16MB (b,s,h,hd)
    short* k_rope = (short*)ws;  ws += (size_t)4096 * 512 * 2;     // 4MB  (b,g,s,hd)
    short* vt     = (short*)ws;  ws += (size_t)4096 * 512 * 2;     // 4MB  (b,g,hd,s)
    short* a_out  = (short*)ws;  ws += (size_t)4096 * 2048 * 2;    // 16MB

    const int M = B_ * S_;  // 4096

    // pre-pass: x cast + all weight transposes
    cast_kernel<<<M * 2048 / 1024, 256, 0, stream>>>(x, xb);
    transpose_all_kernel<<<dim3(80, 32), 256, 0, stream>>>(Wq, Wk, Wv, Wo, Wt, Wot);

    // fused QKV projection + RMSNorm + RoPE + V transpose: 128x384 tiles,
    // 256 uniform blocks = full machine
    qkv_fused_kernel<<<dim3(8, 32), 512, 0, stream>>>(
        xb, Wt, cosb, sinb, qw, kw, q_rope, k_rope, vt);

    // causal GQA flash attention: 256 equal-wall blocks x 512 threads
    attn_kernel<<<256, 512, 0, stream>>>(q_rope, k_rope, vt, a_out);

    // output projection: 128x256-tile phase engine, 256 blocks = full machine
    gemm_oproj_kernel<<<dim3(8, 32), 512, 0, stream>>>(a_out, Wot, out);
}

// Round 10
// 279.111 us; speedup vs baseline: 1.0378x; 1.0378x over previous
//
#include <hip/hip_runtime.h>
#include <hip/hip_bf16.h>
#include <math.h>

#define B_ 2
#define S_ 2048
#define D_ 2048
#define NH_ 16
#define NKV_ 4
#define HD_ 128
#define EPS_ 1e-6f
#define SCALE_ 0.08838834764831845f  // 1/sqrt(128)
#define LOG2E_ 1.4426950408889634f
#define KOFF_ 2048                   // k rows offset in fused Wt
#define VOFF_ 2560                   // v rows offset in fused Wt
#define MINIT_ -1e30f                // finite "-inf" so exp2 paths never NaN

typedef float f32x4 __attribute__((ext_vector_type(4)));
typedef short bf16x8 __attribute__((ext_vector_type(8)));
typedef short short4v __attribute__((ext_vector_type(4)));
typedef float float4v __attribute__((ext_vector_type(4)));
typedef unsigned uint2v __attribute__((ext_vector_type(2)));
typedef unsigned uint4v __attribute__((ext_vector_type(4)));

static __device__ __forceinline__ short f2bf(float f) {
    union { float f; unsigned u; } x{f};
    unsigned r = (x.u + 0x7fff + ((x.u >> 16) & 1)) >> 16;   // RTNE
    return (short)r;
}
static __device__ __forceinline__ float bf2f(short s) {
    union { unsigned u; float f; } x; x.u = ((unsigned)(unsigned short)s) << 16; return x.f;
}
// pack two fp32 -> two bf16 (truncation) in ONE v_perm: lo16=hi16(a), hi16=hi16(b)
static __device__ __forceinline__ unsigned pack_bf2(float a, float b) {
    return __builtin_amdgcn_perm(__builtin_bit_cast(unsigned, b),
                                 __builtin_bit_cast(unsigned, a), 0x07060302u);
}

#define AS1(p) ((const __attribute__((address_space(1))) void*)(p))
#define AS3(p) ((__attribute__((address_space(3))) void*)(p))
static __device__ __forceinline__ void async16(const void* g, void* l) {
    __builtin_amdgcn_global_load_lds(AS1(g), AS3(l), 16, 0, 0);
}
#define SB_() __builtin_amdgcn_sched_barrier(0)

// ---------------------------------------------------------------------------
// fp32 -> bf16 flat cast (for x). 4 elems/thread.
// ---------------------------------------------------------------------------
__global__ __launch_bounds__(256) void cast_kernel(const float* __restrict__ in,
                                                   short* __restrict__ out) {
    size_t i = ((size_t)blockIdx.x * 256 + threadIdx.x) * 4;
    float4v v = *(const float4v*)(in + i);
    short4v o; o.x = f2bf(v.x); o.y = f2bf(v.y); o.z = f2bf(v.z); o.w = f2bf(v.w);
    *(short4v*)(out + i) = o;
}

// ---------------------------------------------------------------------------
// All 4 weight transposes in ONE launch. fp32 [K=2048][N] -> bf16 [N][2048].
// grid (80, 32): bx<32 Wq | <40 Wk | <48 Wv | else Wo.
// ---------------------------------------------------------------------------
__global__ __launch_bounds__(256) void transpose_all_kernel(const float* __restrict__ Wq,
                                                            const float* __restrict__ Wk,
                                                            const float* __restrict__ Wv,
                                                            const float* __restrict__ Wo,
                                                            short* __restrict__ Wt,
                                                            short* __restrict__ Wot) {
    __shared__ float tile[64][65];
    const int bx = blockIdx.x, by = blockIdx.y;
    const float* src; short* dst; int N, nb;
    if (bx < 32)      { src = Wq; dst = Wt;                         N = 2048; nb = bx; }
    else if (bx < 40) { src = Wk; dst = Wt + (size_t)KOFF_ * 2048;  N = 512;  nb = bx - 32; }
    else if (bx < 48) { src = Wv; dst = Wt + (size_t)VOFF_ * 2048;  N = 512;  nb = bx - 40; }
    else              { src = Wo; dst = Wot;                        N = 2048; nb = bx - 48; }
    const int n0 = nb * 64, k0 = by * 64;
    const int tid = threadIdx.x;
    for (int r = 0; r < 16; ++r) {
        int k = r * 4 + (tid >> 6);
        int n = tid & 63;
        tile[k][n] = src[(size_t)(k0 + k) * N + n0 + n];
    }
    __syncthreads();
    for (int r = 0; r < 4; ++r) {
        int n  = r * 16 + (tid >> 4);
        int kk = (tid & 15) * 4;
        short4v o4;
        o4.x = f2bf(tile[kk + 0][n]); o4.y = f2bf(tile[kk + 1][n]);
        o4.z = f2bf(tile[kk + 2][n]); o4.w = f2bf(tile[kk + 3][n]);
        *(short4v*)&dst[(size_t)(n0 + n) * 2048 + k0 + kk] = o4;
    }
}

// ---------------------------------------------------------------------------
// O-proj GEMM: C[4096][2048] fp32 = a_out[4096][2048]bf16 @ Wot[2048][2048]^T.
// Tile 128x256, BK=64, 2 K-tiles/iter, 16 iters. grid (8,32) = 256 blocks.
// (unchanged from round 8)
// ---------------------------------------------------------------------------
__global__ __launch_bounds__(512, 2) void gemm_oproj_kernel(const short* __restrict__ A,
                                                            const short* __restrict__ Bt,
                                                            float* __restrict__ C) {
    __shared__ __align__(16) short smem[49152];   // 96KB
    short* A0 = smem;            // 128x64
    short* A1 = smem + 8192;
    short* B0 = smem + 16384;    // 256x64
    short* B1 = smem + 32768;

    const int tid  = threadIdx.x;
    const int orig = blockIdx.y * 8 + blockIdx.x;       // 0..255
    const int swz  = (orig & 7) * 32 + (orig >> 3);     // XCD chunking (256%8==0)
    const int bn = swz & 7, bm = swz >> 3;
    const int wave = tid >> 6, lane = tid & 63;
    const int quad = lane >> 4, l16 = lane & 15;
    const int wr = wave >> 2, wc = wave & 3;            // 2M x 4N waves

    const short* Ag = A  + (size_t)(bm * 128) * 2048;
    const short* Bg = Bt + (size_t)(bn * 256) * 2048;

    f32x4 acc[4][4];
#pragma unroll
    for (int i = 0; i < 4; ++i)
#pragma unroll
        for (int j = 0; j < 4; ++j) acc[i][j] = (f32x4){0.f, 0.f, 0.f, 0.f};

    bf16x8 a[4][2], b0[2][2], b1[2][2];

    auto stage_half = [&](const short* gpanel, int t, int h, short* lslot) {
#pragma unroll
        for (int u = 0; u < 2; ++u) {
            int ci = u * 512 + tid;
            int r  = ci >> 3;
            int cb = ((ci & 7) * 16) ^ ((r & 7) << 4);
            async16(gpanel + (size_t)(h * 128 + r) * 2048 + t * 64 + (cb >> 1),
                    lslot + h * 8192 + ci * 8);
        }
    };

#define OLDA_(lbuf) \
    _Pragma("unroll") for (int mt = 0; mt < 4; ++mt) \
    _Pragma("unroll") for (int ks = 0; ks < 2; ++ks) { \
        int row_ = wr * 64 + mt * 16 + l16; \
        int cb_  = (ks * 64 + quad * 16) ^ ((row_ & 7) << 4); \
        a[mt][ks] = *(const bf16x8*)&(lbuf)[row_ * 64 + (cb_ >> 1)]; \
    }
#define OLDB_(lbuf, qn, breg) \
    _Pragma("unroll") for (int ntl = 0; ntl < 2; ++ntl) \
    _Pragma("unroll") for (int ks = 0; ks < 2; ++ks) { \
        int row_ = wc * 64 + (qn) * 32 + ntl * 16 + l16; \
        int cb_  = (ks * 64 + quad * 16) ^ ((row_ & 7) << 4); \
        breg[ntl][ks] = *(const bf16x8*)&(lbuf)[row_ * 64 + (cb_ >> 1)]; \
    }
#define OBAR_() __builtin_amdgcn_s_barrier()
#define OMFMA_(qn, breg) do { \
    __builtin_amdgcn_s_setprio(1); \
    _Pragma("unroll") for (int mt = 0; mt < 4; ++mt) \
    _Pragma("unroll") for (int ntl = 0; ntl < 2; ++ntl) \
    _Pragma("unroll") for (int ks = 0; ks < 2; ++ks) \
        acc[mt][(qn) * 2 + ntl] = __builtin_amdgcn_mfma_f32_16x16x32_bf16( \
            a[mt][ks], breg[ntl][ks], acc[mt][(qn) * 2 + ntl], 0, 0, 0); \
    __builtin_amdgcn_s_setprio(0); __builtin_amdgcn_s_barrier(); } while (0)

    // prologue: B0(t0) + A0(t0) = 6 ops; full drain
    stage_half(Bg, 0, 0, B0); stage_half(Bg, 0, 1, B0);
    stage_half(Ag, 0, 0, A0);
    asm volatile("s_waitcnt vmcnt(0)" ::: "memory");
    __builtin_amdgcn_s_barrier();

#pragma unroll 1
    for (int i = 0; i < 16; ++i) {
        const int tE = 2 * i, tO = 2 * i + 1;
        const bool more = (i < 15);

        // P1: stage A1(tO)+B1(tO); read aE, bE-h0; bar; MFMA
        stage_half(Ag, tO, 0, A1);
        stage_half(Bg, tO, 0, B1); stage_half(Bg, tO, 1, B1);
        OLDA_(A0); OLDB_(B0, 0, b0);
        OBAR_();
        OMFMA_(0, b0);

        // P2: stage A0(tE+2); vmcnt(2) drains A1,B1; read bE-h1; bar; MFMA
        if (more) {
            stage_half(Ag, tE + 2, 0, A0);
            asm volatile("s_waitcnt vmcnt(2)" ::: "memory");
        } else {
            asm volatile("s_waitcnt vmcnt(0)" ::: "memory");
        }
        OLDB_(B0, 1, b1);
        OBAR_();
        OMFMA_(1, b1);

        // P3: stage B0(tE+2); read aO, bO-h0; bar; MFMA
        if (more) { stage_half(Bg, tE + 2, 0, B0); stage_half(Bg, tE + 2, 1, B0); }
        OLDA_(A1); OLDB_(B1, 0, b0);
        OBAR_();
        OMFMA_(0, b0);

        // P4: vmcnt(0) drains A0',B0' for next P1; read bO-h1; bar; MFMA
        if (more) { asm volatile("s_waitcnt vmcnt(0)" ::: "memory"); }
        OLDB_(B1, 1, b1);
        OBAR_();
        OMFMA_(1, b1);
    }

    // epilogue: direct fp32 store
#pragma unroll
    for (int mt = 0; mt < 4; ++mt)
#pragma unroll
        for (int nt = 0; nt < 4; ++nt)
#pragma unroll
            for (int j = 0; j < 4; ++j) {
                int row = bm * 128 + wr * 64 + mt * 16 + quad * 4 + j;
                int col = bn * 256 + wc * 64 + nt * 16 + l16;
                C[(size_t)row * 2048 + col] = acc[mt][nt][j];
            }
#undef OLDA_
#undef OLDB_
#undef OBAR_
#undef OMFMA_
}

// ---------------------------------------------------------------------------
// Fused QKV GEMM + RMSNorm + RoPE + V-transpose — r10: r9 main loop (tile
// 128x384, 256 uniform blocks = full machine) + COALESCED epilogue:
//  - per-16-col-chunk sumsq via shfl reduce -> ps[24][128] (12KB LDS)
//  - bf16 C tile at stride 384 (rows 16B-aligned, b128-friendly)
//  - write pass: lane-per-seg -> 256B contiguous global stores (r3 pattern)
// r9's per-(row,head)-thread epilogue caused 3.5x write amplification
// (85MB WRITE_SIZE); this restores ~24.5MB.
// ---------------------------------------------------------------------------
#define QKV_ITERS 16   // K=2048 / (2 K-tiles * 64)

__global__ __launch_bounds__(512, 2) void qkv_fused_kernel(const short* __restrict__ xb,
                                                           const short* __restrict__ Wt,
                                                           const float* __restrict__ cosb,
                                                           const float* __restrict__ sinb,
                                                           const float* __restrict__ qw,
                                                           const float* __restrict__ kw,
                                                           short* __restrict__ q_rope,
                                                           short* __restrict__ k_rope,
                                                           short* __restrict__ vtr) {
    __shared__ __align__(16) short smem[65536];   // 128KB: A0|A1|B0|B1, then ct|ps

    short* A0 = smem;             // [128][64]
    short* A1 = smem + 8192;
    short* B0 = smem + 16384;     // [384][64]
    short* B1 = smem + 40960;

    const int tid  = threadIdx.x;
    const int orig = blockIdx.y * 8 + blockIdx.x;       // 0..255
    const int swz  = (orig & 7) * 32 + (orig >> 3);     // XCD x -> bn=x chunk
    const int bn = swz >> 5, bm = swz & 31;             // bn 0..7, bm 0..31
    const int wave = tid >> 6, lane = tid & 63;
    const int quad = lane >> 4, l16 = lane & 15;
    const int wr = wave >> 2, wc = wave & 3;            // 2M x 4N waves

    const short* Ag = xb + (size_t)(bm * 128) * 2048;
    const short* Bg = Wt + (size_t)(bn * 384) * 2048;

    f32x4 acc[4][6];
#pragma unroll
    for (int i = 0; i < 4; ++i)
#pragma unroll
        for (int j = 0; j < 6; ++j) acc[i][j] = (f32x4){0.f, 0.f, 0.f, 0.f};

    bf16x8 a[4][2], b0[3][2], b1[3][2];

    auto stage_half = [&](const short* gpanel, int t, int h, short* lslot) {
#pragma unroll
        for (int u = 0; u < 2; ++u) {
            int ci = u * 512 + tid;                 // 0..1023
            int r  = ci >> 3;                       // 0..127
            int cb = ((ci & 7) * 16) ^ ((r & 7) << 4);
            async16(gpanel + (size_t)(h * 128 + r) * 2048 + t * 64 + (cb >> 1),
                    lslot + h * 8192 + ci * 8);
        }
    };

#define LDA_(lbuf) \
    _Pragma("unroll") for (int mt = 0; mt < 4; ++mt) \
    _Pragma("unroll") for (int ks = 0; ks < 2; ++ks) { \
        int row_ = wr * 64 + mt * 16 + l16; \
        int cb_  = (ks * 64 + quad * 16) ^ ((row_ & 7) << 4); \
        a[mt][ks] = *(const bf16x8*)&(lbuf)[row_ * 64 + (cb_ >> 1)]; \
    }
#define LDB_(lbuf, qn, breg) \
    _Pragma("unroll") for (int ntl = 0; ntl < 3; ++ntl) \
    _Pragma("unroll") for (int ks = 0; ks < 2; ++ks) { \
        int row_ = wc * 96 + (qn) * 48 + ntl * 16 + l16; \
        int cb_  = (ks * 64 + quad * 16) ^ ((row_ & 7) << 4); \
        breg[ntl][ks] = *(const bf16x8*)&(lbuf)[row_ * 64 + (cb_ >> 1)]; \
    }
#define PH_BAR() do { __builtin_amdgcn_sched_barrier(0); __builtin_amdgcn_s_barrier(); } while (0)
#define PH_MFMA24(qn, breg) do { \
        __builtin_amdgcn_s_setprio(1); \
        _Pragma("unroll") for (int mt = 0; mt < 4; ++mt) \
        _Pragma("unroll") for (int ntl = 0; ntl < 3; ++ntl) \
        _Pragma("unroll") for (int ks = 0; ks < 2; ++ks) \
            acc[mt][(qn) * 3 + ntl] = __builtin_amdgcn_mfma_f32_16x16x32_bf16( \
                a[mt][ks], breg[ntl][ks], acc[mt][(qn) * 3 + ntl], 0, 0, 0); \
        __builtin_amdgcn_s_setprio(0); \
        __builtin_amdgcn_sched_barrier(0); __builtin_amdgcn_s_barrier(); } while (0)

    // prologue: B0(t0) 3u + A0(t0) 1u + A1(t1) 1u; vmcnt(2) leaves A1 in flight
    stage_half(Bg, 0, 0, B0); stage_half(Bg, 0, 1, B0); stage_half(Bg, 0, 2, B0);
    stage_half(Ag, 0, 0, A0);
    stage_half(Ag, 1, 0, A1);
    asm volatile("s_waitcnt vmcnt(2)" ::: "memory");
    __builtin_amdgcn_s_barrier();

#pragma unroll 1
    for (int i = 0; i < QKV_ITERS; ++i) {
        const int tE = 2 * i, tO = 2 * i + 1;
        const bool more = (i < QKV_ITERS - 1);

        // P1: read A0 (all) + B0 n-half 0; stage B1(tO) x3
        LDA_(A0); LDB_(B0, 0, b0);
        stage_half(Bg, tO, 0, B1); stage_half(Bg, tO, 1, B1); stage_half(Bg, tO, 2, B1);
        PH_BAR();
        PH_MFMA24(0, b0);

        // P2: read B0 n-half 1; stage A0'(tE+2); vmcnt drains A1+B1(tO)
        LDB_(B0, 1, b1);
        if (more) {
            stage_half(Ag, tE + 2, 0, A0);
            asm volatile("s_waitcnt vmcnt(2)" ::: "memory");
        } else {
            asm volatile("s_waitcnt vmcnt(0)" ::: "memory");
        }
        PH_BAR();
        PH_MFMA24(1, b1);

        // P3: read A1 (all) + B1 n-half 0; stage B0'(tE+2) x3
        LDA_(A1); LDB_(B1, 0, b0);
        if (more) { stage_half(Bg, tE + 2, 0, B0); stage_half(Bg, tE + 2, 1, B0); stage_half(Bg, tE + 2, 2, B0); }
        PH_BAR();
        PH_MFMA24(0, b0);

        // P4: read B1 n-half 1; stage A1'(tO+2); vmcnt drains A0'+B0'
        LDB_(B1, 1, b1);
        if (more) {
            stage_half(Ag, tO + 2, 0, A1);
            asm volatile("s_waitcnt vmcnt(2)" ::: "memory");
        }
        PH_BAR();
        PH_MFMA24(1, b1);
    }

    // ----------------------- epilogue -----------------------
    // V heads (gh 20..23): direct transposed store from acc, 8B 4-token runs.
#pragma unroll
    for (int mt = 0; mt < 4; ++mt) {
        int tok0 = bm * 128 + wr * 64 + mt * 16 + quad * 4;
        int bb = tok0 >> 11, s0 = tok0 & (S_ - 1);
#pragma unroll
        for (int nt = 0; nt < 6; ++nt) {
            int colh = wc * 96 + nt * 16;          // 16-aligned -> head-uniform
            int gh = bn * 3 + (colh >> 7);
            if (gh >= 20) {
                int g = gh - 20;
                int d = (colh & 127) + l16;
                short4v o4;
                o4.x = f2bf(acc[mt][nt][0]); o4.y = f2bf(acc[mt][nt][1]);
                o4.z = f2bf(acc[mt][nt][2]); o4.w = f2bf(acc[mt][nt][3]);
                *(short4v*)&vtr[((size_t)(bb * NKV_ + g) * HD_ + d) * S_ + s0] = o4;
            }
        }
    }
    if (bn * 3 >= 20) return;   // bn=7: pure-V block, done

    // per-16-col-chunk sumsq -> ps[chunk][row] (chunk = wc*6+nt, 24 chunks)
    short* ct = smem;                              // [128][384] bf16 C tile
    float* ps = (float*)(smem + 49152);            // [24][128] chunk sumsq
    {
#pragma unroll
        for (int nt = 0; nt < 6; ++nt) {
            float s[4][4];
#pragma unroll
            for (int mt = 0; mt < 4; ++mt)
#pragma unroll
                for (int j = 0; j < 4; ++j)
                    s[mt][j] = acc[mt][nt][j] * acc[mt][nt][j];
#pragma unroll
            for (int off = 1; off < 16; off <<= 1)
#pragma unroll
                for (int mt = 0; mt < 4; ++mt)
#pragma unroll
                    for (int j = 0; j < 4; ++j)
                        s[mt][j] += __shfl_xor(s[mt][j], off);
            if (l16 == 0) {
#pragma unroll
                for (int mt = 0; mt < 4; ++mt)
#pragma unroll
                    for (int j = 0; j < 4; ++j)
                        ps[(wc * 6 + nt) * 128 + wr * 64 + mt * 16 + quad * 4 + j] = s[mt][j];
            }
        }
    }
    // bf16 C tile into LDS, stride 384 (rows 16B-aligned)
#pragma unroll
    for (int mt = 0; mt < 4; ++mt)
#pragma unroll
        for (int nt = 0; nt < 6; ++nt)
#pragma unroll
            for (int j = 0; j < 4; ++j)
                ct[(wr * 64 + mt * 16 + quad * 4 + j) * 384 + wc * 96 + nt * 16 + l16]
                    = f2bf(acc[mt][nt][j]);
    __syncthreads();

    // write pass: f -> (seg, row, head); consecutive lanes = consecutive segs
    // -> 256B contiguous global stores. 12 iters x 512 = 6144 = 384 rh x 16.
#pragma unroll 1
    for (int it = 0; it < 12; ++it) {
        int f = it * 512 + tid;
        int seg = f & 15;
        int rh  = f >> 4;              // 0..383
        int row = rh & 127, head = rh >> 7;
        int gh = bn * 3 + head;
        if (gh >= 20) continue;        // bn=6 head2 is V (already stored)
        const bool isQ = gh < 16;
        const float osc = isQ ? (SCALE_ * LOG2E_) : 1.0f;
        const float* w = isQ ? qw : kw;
        float ss = 0.f;
#pragma unroll
        for (int c = 0; c < 8; ++c) ss += ps[(head * 8 + c) * 128 + row];
        float rstd = rsqrtf(ss * (1.0f / HD_) + EPS_);
        int tok = bm * 128 + row;
        int bb = tok >> 11, s = tok & (S_ - 1);
        int c0 = seg * 8, p0 = (seg ^ 8) * 8;
        bf16x8 ta = *(const bf16x8*)&ct[row * 384 + head * 128 + c0];
        bf16x8 tb = *(const bf16x8*)&ct[row * 384 + head * 128 + p0];
        float sgn = (seg < 8) ? -1.0f : 1.0f;
        float4v cs0 = *(const float4v*)&cosb[(size_t)s * HD_ + c0];
        float4v cs1 = *(const float4v*)&cosb[(size_t)s * HD_ + c0 + 4];
        float4v sn0 = *(const float4v*)&sinb[(size_t)s * HD_ + c0];
        float4v sn1 = *(const float4v*)&sinb[(size_t)s * HD_ + c0 + 4];
        float ov[8];
#pragma unroll
        for (int i = 0; i < 8; ++i) {
            float n1 = bf2f(ta[i]) * rstd * w[c0 + i];
            float n2 = bf2f(tb[i]) * rstd * w[p0 + i];
            float cs = (i < 4) ? cs0[i & 3] : cs1[i & 3];
            float sn = (i < 4) ? sn0[i & 3] : sn1[i & 3];
            ov[i] = (n1 * cs + sgn * n2 * sn) * osc;
        }
        uint4v wv;
#pragma unroll
        for (int i2 = 0; i2 < 4; ++i2)
            wv[i2] = ((unsigned)(unsigned short)f2bf(ov[2 * i2])) |
                     ((unsigned)(unsigned short)f2bf(ov[2 * i2 + 1]) << 16);
        short* dst = isQ
            ? q_rope + ((size_t)(bb * S_ + s) * NH_ + gh) * HD_ + c0
            : k_rope + ((size_t)(bb * NKV_ + (gh - 16)) * S_ + s) * HD_ + c0;
        *(uint4v*)dst = wv;
    }
#undef LDA_
#undef LDB_
#undef PH_BAR
#undef PH_MFMA24
}

// ---------------------------------------------------------------------------
// Flash causal GQA attention v7: dual-stream K parity split (unchanged r7).
// ---------------------------------------------------------------------------
__global__ __launch_bounds__(512, 1) void attn_kernel(const short* __restrict__ qr,
                                                      const short* __restrict__ kg,
                                                      const short* __restrict__ vt,
                                                      short* __restrict__ aout) {
    __shared__ __align__(16) short Ks[2][2][8192];   // [stream][dbuf][64 keys x 128 d]
    __shared__ __align__(16) short Vs[2][2][8192];   // [stream][dbuf][128 d x 64 keys]

    const int lin = blockIdx.x;        // 0..255 ; lin&7 = (b,g) = XCD id -> KV L2-local
    const int b  = lin & 1;
    const int g  = (lin >> 1) & 3;
    const int hq = (lin >> 3) & 3;
    const int pr = lin >> 5;           // 0..7
    const int h  = g * 4 + hq;

    const int wave = threadIdx.x >> 6, lane = threadIdx.x & 63;
    const int quad = lane >> 4, l16 = lane & 15;
    const int half = wave >> 2;        // 0 = stream A (even kt), 1 = B (odd kt)
    const int ww   = wave & 3;

    const short* kbase = kg + (size_t)(b * NKV_ + g) * S_ * HD_;
    const short* vbase = vt + (size_t)(b * NKV_ + g) * HD_ * S_;

    // stage one 64-key K/V unit; all 8 waves participate (2+2 async16 each)
    auto stage = [&](int kt, short* Kd, short* Vd) {
        const short* kt_base = kbase + (size_t)kt * 64 * HD_;
        const short* vt_base = vbase + kt * 64;
#pragma unroll
        for (int t = 0; t < 2; ++t) {
            int ci  = (wave * 2 + t) * 64 + lane;
            int key = ci >> 4;
            int c   = (ci & 15) ^ ((key ^ (key >> 2)) & 15);
            async16(kt_base + key * HD_ + c * 8, Kd + ci * 8);
        }
#pragma unroll
        for (int t = 0; t < 2; ++t) {
            int ci = (wave * 2 + t) * 64 + lane;
            int d  = ci >> 3;
            int c  = (ci & 7) ^ (d & 7);
            async16(vt_base + (size_t)d * S_ + c * 8, Vd + ci * 8);
        }
    };

#pragma unroll 1
    for (int ph = 0; ph < 2; ++ph) {
        const int qt    = ph ? (15 - pr) : pr;     // 128-row Q tile
        const int nhalf = qt + 1;                  // units per stream
        const int qrow0 = qt * 128 + ww * 16 + l16;
        const int qrow1 = qrow0 + 64;

        bf16x8 qf[2][4];
#pragma unroll
        for (int qs = 0; qs < 2; ++qs) {
            const short* qp = qr + ((size_t)(b * S_ + (qs ? qrow1 : qrow0)) * NH_ + h) * HD_;
#pragma unroll
            for (int ks = 0; ks < 4; ++ks)
                qf[qs][ks] = *(const bf16x8*)(qp + ks * 32 + quad * 8);
        }

        f32x4 o[2][8];
#pragma unroll
        for (int qs = 0; qs < 2; ++qs)
#pragma unroll
            for (int i = 0; i < 8; ++i) o[qs][i] = (f32x4){0.f, 0.f, 0.f, 0.f};
        float m_i[2] = {MINIT_, MINIT_};
        float l_i[2] = {0.f, 0.f};

        // prologue: first unit of each stream
        stage(0, Ks[0][0], Vs[0][0]);
        stage(1, Ks[1][0], Vs[1][0]);
        int buf = 0;
#pragma unroll 1
        for (int i = 0; i < nhalf; ++i) {
            __syncthreads();   // drains vmcnt: staged units landed; prev reads done
            if (i + 1 < nhalf) {
                stage(2 * i + 2, Ks[0][buf ^ 1], Vs[0][buf ^ 1]);
                stage(2 * i + 3, Ks[1][buf ^ 1], Vs[1][buf ^ 1]);
            }
            const short* Kb = Ks[half][buf];
            const short* Vb = Vs[half][buf];
            const int ktm = 2 * i + half;

            f32x4 acc[2][4];
#pragma unroll
            for (int qs = 0; qs < 2; ++qs)
#pragma unroll
                for (int t = 0; t < 4; ++t) acc[qs][t] = (f32x4){0.f, 0.f, 0.f, 0.f};
            __builtin_amdgcn_s_setprio(1);
#pragma unroll
            for (int t = 0; t < 4; ++t) {
                int lk = ((t >> 1) << 5) + ((l16 >> 2) << 3) + ((t & 1) << 2) + (l16 & 3);
                const short* kp = &Kb[lk * 128];
                int pm = (lk ^ (lk >> 2)) & 15;
#pragma unroll
                for (int ks = 0; ks < 4; ++ks) {
                    bf16x8 kf = *(const bf16x8*)(kp + (((ks * 4 + quad) ^ pm) * 8));
                    acc[0][t] = __builtin_amdgcn_mfma_f32_16x16x32_bf16(kf, qf[0][ks], acc[0][t], 0, 0, 0);
                    acc[1][t] = __builtin_amdgcn_mfma_f32_16x16x32_bf16(kf, qf[1][ks], acc[1][t], 0, 0, 0);
                }
            }
            __builtin_amdgcn_s_setprio(0);
            const int key_base = ktm * 64;
#pragma unroll
            for (int qs = 0; qs < 2; ++qs) {
                int qmin = qt * 128 + qs * 64 + ww * 16;
                int qrow = qs ? qrow1 : qrow0;
                if (key_base + 63 > qmin) {
#pragma unroll
                    for (int t = 0; t < 4; ++t)
#pragma unroll
                        for (int j = 0; j < 4; ++j) {
                            int kl = key_base + ((t >> 1) << 5) + (quad << 3) + ((t & 1) << 2) + j;
                            if (kl > qrow) acc[qs][t][j] = -INFINITY;
                        }
                }
            }
            unsigned pk[2][2][4];
#pragma unroll
            for (int qs = 0; qs < 2; ++qs) {
                float mx = m_i[qs];
#pragma unroll
                for (int t = 0; t < 4; ++t)
#pragma unroll
                    for (int j = 0; j < 4; ++j) mx = fmaxf(mx, acc[qs][t][j]);
                mx = fmaxf(mx, __shfl_xor(mx, 16));
                mx = fmaxf(mx, __shfl_xor(mx, 32));
                float al = __builtin_amdgcn_exp2f(m_i[qs] - mx);
                m_i[qs] = mx;
                float rs = 0.f;
                float p[4][4];
#pragma unroll
                for (int t = 0; t < 4; ++t)
#pragma unroll
                    for (int j = 0; j < 4; ++j) {
                        float e = __builtin_amdgcn_exp2f(acc[qs][t][j] - mx);
                        p[t][j] = e;
                        rs += e;
                    }
                rs += __shfl_xor(rs, 16);
                rs += __shfl_xor(rs, 32);
                l_i[qs] = al * l_i[qs] + rs;
#pragma unroll
                for (int d8 = 0; d8 < 8; ++d8)
#pragma unroll
                    for (int j = 0; j < 4; ++j) o[qs][d8][j] *= al;
#pragma unroll
                for (int grp = 0; grp < 2; ++grp) {
                    pk[qs][grp][0] = pack_bf2(p[2 * grp][0],     p[2 * grp][1]);
                    pk[qs][grp][1] = pack_bf2(p[2 * grp][2],     p[2 * grp][3]);
                    pk[qs][grp][2] = pack_bf2(p[2 * grp + 1][0], p[2 * grp + 1][1]);
                    pk[qs][grp][3] = pack_bf2(p[2 * grp + 1][2], p[2 * grp + 1][3]);
                }
            }
            __builtin_amdgcn_s_setprio(1);
#pragma unroll
            for (int grp = 0; grp < 2; ++grp) {
                union { unsigned u[4]; bf16x8 v; } pb0, pb1;
#pragma unroll
                for (int i2 = 0; i2 < 4; ++i2) { pb0.u[i2] = pk[0][grp][i2]; pb1.u[i2] = pk[1][grp][i2]; }
#pragma unroll
                for (int d8 = 0; d8 < 8; ++d8) {
                    int d = d8 * 16 + l16;
                    bf16x8 vf = *(const bf16x8*)&Vb[d * 64 + (((grp * 4 + quad) ^ (d & 7)) * 8)];
                    o[0][d8] = __builtin_amdgcn_mfma_f32_16x16x32_bf16(vf, pb0.v, o[0][d8], 0, 0, 0);
                    o[1][d8] = __builtin_amdgcn_mfma_f32_16x16x32_bf16(vf, pb1.v, o[1][d8], 0, 0, 0);
                }
            }
            __builtin_amdgcn_s_setprio(0);
            buf ^= 1;
        }

        // ---- merge A/B partials via LDS exchange (staging buffers dead) ----
        __syncthreads();
        float* exch = (float*)(ww < 2 ? &Ks[0][0][0] : &Vs[0][0][0]);
        float* slot = exch + ((size_t)((ww & 1) * 64 + lane) * 68);
        if (half == 1) {
#pragma unroll
            for (int qs = 0; qs < 2; ++qs) {
#pragma unroll
                for (int d8 = 0; d8 < 8; ++d8)
#pragma unroll
                    for (int j = 0; j < 4; ++j)
                        slot[qs * 32 + d8 * 4 + j] = o[qs][d8][j];
                slot[64 + qs] = m_i[qs];
                slot[66 + qs] = l_i[qs];
            }
        }
        __syncthreads();
        if (half == 0) {
#pragma unroll
            for (int qs = 0; qs < 2; ++qs) {
                float mB = slot[64 + qs], lB = slot[66 + qs];
                float m  = fmaxf(m_i[qs], mB);
                float wA = __builtin_amdgcn_exp2f(m_i[qs] - m);
                float wB = __builtin_amdgcn_exp2f(mB - m);
                float il = 1.0f / (l_i[qs] * wA + lB * wB);
                int qrow = qs ? qrow1 : qrow0;
                short* op = aout + ((size_t)(b * S_ + qrow) * NH_ + h) * HD_ + quad * 4;
#pragma unroll
                for (int d8 = 0; d8 < 8; ++d8) {
                    float v0 = (o[qs][d8][0] * wA + slot[qs * 32 + d8 * 4 + 0] * wB) * il;
                    float v1 = (o[qs][d8][1] * wA + slot[qs * 32 + d8 * 4 + 1] * wB) * il;
                    float v2 = (o[qs][d8][2] * wA + slot[qs * 32 + d8 * 4 + 2] * wB) * il;
                    float v3 = (o[qs][d8][3] * wA + slot[qs * 32 + d8 * 4 + 3] * wB) * il;
                    uint2v wv;
                    wv.x = ((unsigned)(unsigned short)f2bf(v0)) |
                           ((unsigned)(unsigned short)f2bf(v1) << 16);
                    wv.y = ((unsigned)(unsigned short)f2bf(v2)) |
                           ((unsigned)(unsigned short)f2bf(v3) << 16);
                    *(uint2v*)(op + d8 * 16) = wv;
                }
            }
        }
        __syncthreads();   // exchange fully read before next phase restages
    }
}

// ---------------------------------------------------------------------------
extern "C" void kernel_launch(void* const* d_in, const int* in_sizes, int n_in,
                              void* d_out, int out_size, void* d_ws, size_t ws_size,
                              hipStream_t stream) {
    (void)in_sizes; (void)n_in; (void)out_size; (void)ws_size;
    const float* x    = (const float*)d_in[0];
    const float* cosb = (const float*)d_in[1];
    const float* sinb = (const float*)d_in[2];
    const float* Wq   = (const float*)d_in[3];
    const float* Wk   = (const float*)d_in[4];
    const float* Wv   = (const float*)d_in[5];
    const float* Wo   = (const float*)d_in[6];
    const float* qw   = (const float*)d_in[7];
    const float* kw   = (const float*)d_in[8];
    float* out = (float*)d_out;

    char* ws = (char*)d_ws;
    short* xb     = (short*)ws;  ws += (size_t)4096 * 2048 * 2;    // 16MB
    short* Wt     = (short*)ws;  ws += (size_t)3072 * 2048 * 2;    // 12MB [n][k]
    short* Wot    = (short*)ws;  ws += (size_t)2048 * 2048 * 2;    // 8MB  [n][k]
    short* q_rope = (short*)ws;  ws += (size_t)4096 * 2048 * 2;    // 16MB (b,s,h,hd)
    short* k_rope = (short*)ws;  ws += (size_t)4096 * 512 * 2;     // 4MB  (b,g,s,hd)
    short* vt     = (short*)ws;  ws += (size_t)4096 * 512 * 2;     // 4MB  (b,g,hd,s)
    short* a_out  = (short*)ws;  ws += (size_t)4096 * 2048 * 2;    // 16MB

    const int M = B_ * S_;  // 4096

    // pre-pass: x cast + all weight transposes
    cast_kernel<<<M * 2048 / 1024, 256, 0, stream>>>(x, xb);
    transpose_all_kernel<<<dim3(80, 32), 256, 0, stream>>>(Wq, Wk, Wv, Wo, Wt, Wot);

    // fused QKV projection + RMSNorm + RoPE + V transpose: 128x384 tiles,
    // 256 uniform blocks, coalesced epilogue
    qkv_fused_kernel<<<dim3(8, 32), 512, 0, stream>>>(
        xb, Wt, cosb, sinb, qw, kw, q_rope, k_rope, vt);

    // causal GQA flash attention: 256 equal-wall blocks x 512 threads
    attn_kernel<<<256, 512, 0, stream>>>(q_rope, k_rope, vt, a_out);

    // output projection: 128x256-tile phase engine, 256 blocks = full machine
    gemm_oproj_kernel<<<dim3(8, 32), 512, 0, stream>>>(a_out, Wot, out);
}